// Round 15
// baseline (471.294 us; speedup 1.0000x reference)
//
#include <hip/hip_runtime.h>
#include <cstdint>
#include <cstddef>

typedef unsigned short u16;
typedef __attribute__((ext_vector_type(8))) short short8;
typedef __attribute__((ext_vector_type(4))) float f32x4;

__device__ __forceinline__ f32x4 mfma16(short8 a, short8 b, f32x4 c){
  return __builtin_amdgcn_mfma_f32_16x16x32_bf16(a, b, c, 0, 0, 0);
}
__device__ __forceinline__ float bf2f(u16 u){
  unsigned v = ((unsigned)u) << 16; float f; __builtin_memcpy(&f, &v, 4); return f;
}
__device__ __forceinline__ u16 f2bf(float f){
  unsigned u; __builtin_memcpy(&u, &f, 4);
  u += 0x7FFFu + ((u >> 16) & 1u);
  return (u16)(u >> 16);
}
__device__ __forceinline__ float sigf(float x){ return 1.f / (1.f + __expf(-x)); }

// ---------------- fp32 -> zero-padded bf16 conversion ----------------
struct CvtD { const float* s; u16* d; int M, K, Mp, Kp; };
struct CvtTab { CvtD t[10]; };

__global__ void cvt_all(CvtTab tab){
  CvtD de = tab.t[blockIdx.y];
  int total = de.Mp * de.Kp;
  for (int i = blockIdx.x * blockDim.x + threadIdx.x; i < total; i += gridDim.x * blockDim.x){
    int r = i / de.Kp, c = i - r * de.Kp;
    float v = (r < de.M && c < de.K) ? de.s[(size_t)r * de.K + c] : 0.f;
    de.d[i] = f2bf(v);
  }
}

// q_rel gather
__global__ void gather_qrel(const u16* __restrict__ mbf, const float* __restrict__ m32,
                            const int* __restrict__ trip, u16* __restrict__ qbf,
                            float* __restrict__ q32){
  int i = blockIdx.x * blockDim.x + threadIdx.x;
  if (i < 2048 * 256){
    int b = i >> 8, c = i & 255;
    int rel = trip[b * 3 + 1];
    qbf[i] = mbf[rel * 256 + c];
    if (c < 200) q32[b * 200 + c] = m32[rel * 200 + c];
  }
}

// ---------------- compaction: t-major pair list of (t,b) with t < cur_ts[b] ---------
__global__ void cntt_k(const int* __restrict__ cur_ts, int* __restrict__ cntt,
                       float* __restrict__ out0){
  int t = blockIdx.x;
  __shared__ int psum[256];
  int tid = threadIdx.x, s = 0;
  #pragma unroll
  for (int k = 0; k < 8; ++k) s += (cur_ts[tid * 8 + k] > t) ? 1 : 0;
  psum[tid] = s; __syncthreads();
  for (int st = 128; st > 0; st >>= 1){
    if (tid < st) psum[tid] += psum[tid + st];
    __syncthreads();
  }
  if (tid == 0){
    cntt[t] = psum[0];
    if (t == 0){ out0[0] = 0.f; out0[1] = 0.f; }
  }
}
__global__ void toff_k(const int* __restrict__ cntt, int* __restrict__ toff){
  if (threadIdx.x == 0){
    int run = 0;
    for (int t = 0; t < 32; ++t){ toff[t] = run; run += cntt[t]; }
    toff[32] = run;
  }
}
__global__ void fill_pairs_t(const int* __restrict__ cur_ts, const int* __restrict__ toff,
                             int* __restrict__ pairs){
  int t = blockIdx.x;
  __shared__ int psum[256];
  int tid = threadIdx.x;
  int loc[8]; int tsum = 0;
  #pragma unroll
  for (int k = 0; k < 8; ++k){ loc[k] = (cur_ts[tid * 8 + k] > t) ? 1 : 0; tsum += loc[k]; }
  psum[tid] = tsum; __syncthreads();
  for (int st = 1; st < 256; st <<= 1){
    int v = (tid >= st) ? psum[tid - st] : 0;
    __syncthreads();
    psum[tid] += v;
    __syncthreads();
  }
  int run = psum[tid] - tsum + toff[t];
  #pragma unroll
  for (int k = 0; k < 8; ++k)
    if (loc[k]){ pairs[run] = t * 2048 + tid * 8 + k; ++run; }
}

// ---------------- register-direct MFMA GEMM: no LDS, no barriers -------------------
// Each wave owns a 64x64 subtile; fragments loaded global->VGPR (operands are
// L2/L3-resident at our sizes; lanes sharing fr form full 64B lines). K fully
// unrolled via KT so per-step addresses fold into offset:N immediates.
// MODE 0: fp32/bf16 C (z-batchable incl. per-z Mreal/ldc16).  MODE 1: ph + match_loss.
// MODE 2: score epilogue.  MODE 3: compacted gi (row-indirect out via pairs).
template<int MODE, int GROUP, int KT>
__global__ __launch_bounds__(256) void gemm_bt(
    const u16* A, int lda,
    const u16* B, int ldb,
    int K, int Mreal, int Nreal,
    const float* bias,
    float* C32,
    u16* C16, int ldc16,
    const float* __restrict__ extra,
    const float* __restrict__ extra2,
    const int* __restrict__ trip,
    float* __restrict__ loss,
    const int* __restrict__ tcnt,
    const u16* A2, const u16* B2, const float* bias2, float* C32b, u16* C16b,
    int Mreal2, int ldc16b)
{
  __shared__ float red[256];
  const int tid = threadIdx.x;
  const int wave = tid >> 6, lane = tid & 63;

  if (MODE == 0 && blockIdx.z){
    A = A2; B = B2; bias = bias2; C32 = C32b; C16 = C16b;
    Mreal = Mreal2; ldc16 = ldc16b;
  }

  const int gx = gridDim.x, gy = gridDim.y;
  const int nwg = gx * gy;
  int orig = blockIdx.y * gx + blockIdx.x;
  int q = nwg >> 3, r8 = nwg & 7;
  int xcd = orig & 7, idx = orig >> 3;
  int fid = (xcd < r8 ? xcd * (q + 1) : r8 * (q + 1) + (xcd - r8) * q) + idx;
  int mx, my;
  if (GROUP == 0){ my = fid / gx; mx = fid - my * gx; }
  else           { mx = fid / gy; my = fid - mx * gy; }

  const int m0 = my * 128, n0 = mx * 128;

  int Mg_ = Mreal;
  if (MODE == 3) Mg_ = tcnt[32];
  if (m0 >= Mg_) return;

  const int wm = (wave >> 1) * 64, wn = (wave & 1) * 64;
  const int fr = lane & 15, fkg = lane >> 4;

  const u16* Ab = A + (size_t)(m0 + wm + fr) * lda + fkg * 8;
  const u16* Bb = B + (size_t)(n0 + wn + fr) * ldb + fkg * 8;

  f32x4 acc[4][4];
  #pragma unroll
  for (int i = 0; i < 4; ++i)
    #pragma unroll
    for (int j = 0; j < 4; ++j) acc[i][j] = (f32x4){0.f, 0.f, 0.f, 0.f};

  #pragma unroll
  for (int kt = 0; kt < KT; ++kt){
    short8 av[4], bv[4];
    #pragma unroll
    for (int i = 0; i < 4; ++i){
      av[i] = *(const short8*)(Ab + (size_t)(i * 16) * lda + kt * 32);
      bv[i] = *(const short8*)(Bb + (size_t)(i * 16) * ldb + kt * 32);
    }
    #pragma unroll
    for (int i = 0; i < 4; ++i)
      #pragma unroll
      for (int j = 0; j < 4; ++j)
        acc[i][j] = mfma16(av[i], bv[j], acc[i][j]);
  }

  if (MODE == 2){
    float lsum = 0.f;
    #pragma unroll
    for (int i = 0; i < 4; ++i){
      #pragma unroll
      for (int r = 0; r < 4; ++r){
        int row = m0 + wm + i * 16 + (lane >> 4) * 4 + r;
        int tcol = trip[row * 3 + 2];
        #pragma unroll
        for (int j = 0; j < 4; ++j){
          int col = n0 + wn + j * 16 + fr;
          if (col < Nreal){
            float v = acc[i][j][r];
            float e = __expf(-fabsf(v));
            float inv = __builtin_amdgcn_rcpf(1.f + e);
            C32[2 + (size_t)row * Nreal + col] = (v >= 0.f) ? inv : e * inv;
            float x = (tcol == col) ? v : -v;
            lsum += fminf(x, 0.f) - __logf(1.f + e);
          }
        }
      }
    }
    red[tid] = lsum;
    __syncthreads();
    for (int s = 128; s > 0; s >>= 1){
      if (tid < s) red[tid] += red[tid + s];
      __syncthreads();
    }
    if (tid == 0) atomicAdd(loss, -red[0] * (1.f / 20480000.f));
    return;
  }

  if (MODE == 3){
    #pragma unroll
    for (int i = 0; i < 4; ++i){
      #pragma unroll
      for (int r = 0; r < 4; ++r){
        int row = m0 + wm + i * 16 + (lane >> 4) * 4 + r;
        if (row < Mg_){
          int orow = trip[row];            // pairs[]: t*2048+b
          #pragma unroll
          for (int j = 0; j < 4; ++j){
            int col = n0 + wn + j * 16 + fr;
            if (col < Nreal)
              C16[(size_t)orow * ldc16 + col] = f2bf(acc[i][j][r] + bias[col]);
          }
        }
      }
    }
    return;
  }

  if (MODE == 1){
    float lsum = 0.f;
    #pragma unroll
    for (int i = 0; i < 4; ++i){
      #pragma unroll
      for (int j = 0; j < 4; ++j){
        int col = n0 + wn + j * 16 + fr;
        float bvl = (col < Nreal) ? bias[col] : 0.f;
        #pragma unroll
        for (int r = 0; r < 4; ++r){
          int row = m0 + wm + i * 16 + (lane >> 4) * 4 + r;
          if (col < Nreal){
            float pv = 0.1f * (acc[i][j][r] + bvl) + extra[(size_t)row * Nreal + col];
            C32[(size_t)row * Nreal + col] = pv;
            C16[(size_t)row * ldc16 + col] = f2bf(pv);
            float d = pv - extra2[(size_t)row * Nreal + col];
            lsum += d * d;
          } else {
            C16[(size_t)row * ldc16 + col] = 0;
          }
        }
      }
    }
    red[tid] = lsum;
    __syncthreads();
    for (int s = 128; s > 0; s >>= 1){
      if (tid < s) red[tid] += red[tid + s];
      __syncthreads();
    }
    if (tid == 0) atomicAdd(loss, red[0] * (1.f / 409600.f));
    return;
  }

  #pragma unroll
  for (int i = 0; i < 4; ++i){
    #pragma unroll
    for (int j = 0; j < 4; ++j){
      int col = n0 + wn + j * 16 + fr;
      float bvl = 0.f;
      if (bias && col < Nreal) bvl = bias[col];
      #pragma unroll
      for (int r = 0; r < 4; ++r){
        int row = m0 + wm + i * 16 + (lane >> 4) * 4 + r;
        float v = acc[i][j][r] + bvl;
        if (C32 && row < Mreal && col < Nreal) C32[(size_t)row * Nreal + col] = v;
        if (C16) C16[(size_t)row * ldc16 + col] =
            (row < Mreal && col < Nreal) ? f2bf(v) : (u16)0;
      }
    }
  }
}

// ---------------- compacted masked softmax over R=460 (single dispatch) -------------
__global__ __launch_bounds__(256) void softmax_c(
    const float* __restrict__ part, const float* __restrict__ base,
    const int* __restrict__ pairs, const int* __restrict__ toff,
    u16* __restrict__ aout)
{
  int wave = threadIdx.x >> 6, lane = threadIdx.x & 63;
  int hi = toff[32];
  for (int j = blockIdx.x * 4 + wave; j < hi; j += gridDim.x * 4){
    int p = pairs[j];
    int b = p & 2047, t = p >> 11;
    const float* pr = part + (size_t)b * 14720 + t * 460;
    const float* br = base + (size_t)b * 460;
    int r0 = lane * 8;
    float vals[8];
    if (lane < 57){
      float4 pa = *(const float4*)(pr + r0);
      float4 pb = *(const float4*)(pr + r0 + 4);
      float4 ba = *(const float4*)(br + r0);
      float4 bb = *(const float4*)(br + r0 + 4);
      float pv[8] = {pa.x, pa.y, pa.z, pa.w, pb.x, pb.y, pb.z, pb.w};
      float bw[8] = {ba.x, ba.y, ba.z, ba.w, bb.x, bb.y, bb.z, bb.w};
      #pragma unroll
      for (int u = 0; u < 8; ++u){
        float a = pv[u] * bw[u];
        bool valid = (r0 + u) < 460;
        vals[u] = (!valid) ? -__builtin_inff() : ((a == 0.f) ? -1000000000.0f : a);
      }
    } else {
      #pragma unroll
      for (int u = 0; u < 8; ++u){
        int r = r0 + u;
        if (r < 460){
          float a = pr[r] * br[r];
          vals[u] = (a == 0.f) ? -1000000000.0f : a;
        } else vals[u] = -__builtin_inff();
      }
    }
    float m = vals[0];
    #pragma unroll
    for (int u = 1; u < 8; ++u) m = fmaxf(m, vals[u]);
    #pragma unroll
    for (int s = 1; s < 64; s <<= 1) m = fmaxf(m, __shfl_xor(m, s));
    float e[8]; float sum = 0.f;
    #pragma unroll
    for (int u = 0; u < 8; ++u){
      float x = vals[u];
      float ev = (x == -__builtin_inff()) ? 0.f : __expf(x - m);
      e[u] = ev; sum += ev;
    }
    #pragma unroll
    for (int s = 1; s < 64; s <<= 1) sum += __shfl_xor(sum, s);
    float inv = __builtin_amdgcn_rcpf(sum);
    union { u16 o[8]; uint4 v; } pk;
    #pragma unroll
    for (int u = 0; u < 8; ++u) pk.o[u] = f2bf(e[u] * inv);
    *(uint4*)(aout + (size_t)j * 512 + r0) = pk.v;
  }
}

// ---------------- GRU recurrence v3: 256 blocks x 8 rows x 8 waves ------------------
__global__ __launch_bounds__(512, 2) void gru_scan3(
    const u16* __restrict__ gi_all,
    const u16* __restrict__ Whh,
    const float* __restrict__ bhh,
    const int* __restrict__ cur_ts,
    float* __restrict__ hout)
{
  __shared__ u16 hbf[16 * 256];
  __shared__ float hf[8 * 200];
  __shared__ float ghs[8][648];
  __shared__ u16 gis[2][8 * 640];
  __shared__ float bhs[600];
  __shared__ int cts[8];
  const int tid = threadIdx.x, wave = tid >> 6, lane = tid & 63;
  const int rb = blockIdx.x * 8;
  const int fr = lane & 15, fkg = lane >> 4;
  const int fk = fkg * 8;

  for (int i = tid; i < 16 * 256; i += 512) hbf[i] = 0;
  for (int i = tid; i < 8 * 200; i += 512) hf[i] = 0.f;
  for (int i = tid; i < 600; i += 512) bhs[i] = bhh[i];
  if (tid < 8) cts[tid] = cur_ts[rb + tid];
  __syncthreads();
  int Trun = 0;
  #pragma unroll
  for (int r = 0; r < 8; ++r) Trun = max(Trun, cts[r]);

  short8 wb[5][7];
  #pragma unroll
  for (int f = 0; f < 5; ++f)
    #pragma unroll
    for (int ks = 0; ks < 7; ++ks)
      wb[f][ks] = *(const short8*)(Whh + (size_t)(wave * 80 + f * 16 + fr) * 256 + ks * 32 + fk);

  if (Trun > 0){
    const u16* src = gi_all + (size_t)rb * 640;
    __builtin_amdgcn_global_load_lds(
        (const __attribute__((address_space(1))) void*)(src + tid * 8),
        (__attribute__((address_space(3))) void*)(&gis[0][0] + tid * 8), 16, 0, 0);
    if (tid < 128)
      __builtin_amdgcn_global_load_lds(
          (const __attribute__((address_space(1))) void*)(src + (512 + tid) * 8),
          (__attribute__((address_space(3))) void*)(&gis[0][0] + (512 + tid) * 8), 16, 0, 0);
  }
  __syncthreads();

  const int grow = wave;
  const int crow = (Trun > 0) ? cts[grow] : 0;

  for (int t = 0; t < Trun; ++t){
    f32x4 acc[5];
    #pragma unroll
    for (int f = 0; f < 5; ++f) acc[f] = (f32x4){0.f, 0.f, 0.f, 0.f};
    #pragma unroll
    for (int ks = 0; ks < 7; ++ks){
      short8 av = *(const short8*)(hbf + ((fr * 256 + ks * 32 + fk) ^ ((fr & 7) << 3)));
      #pragma unroll
      for (int f = 0; f < 5; ++f)
        acc[f] = mfma16(av, wb[f][ks], acc[f]);
    }
    if (fkg < 2){
      #pragma unroll
      for (int f = 0; f < 5; ++f){
        int col = wave * 80 + f * 16 + fr;
        #pragma unroll
        for (int r = 0; r < 4; ++r)
          ghs[fkg * 4 + r][col] = acc[f][r];
      }
    }
    __builtin_amdgcn_sched_barrier(0);
    asm volatile("s_waitcnt vmcnt(0) lgkmcnt(0)" ::: "memory");
    __builtin_amdgcn_sched_barrier(0);
    __builtin_amdgcn_s_barrier();
    __builtin_amdgcn_sched_barrier(0);

    if (t + 1 < Trun){
      const u16* src = gi_all + ((size_t)(t + 1) * 2048 + rb) * 640;
      u16* dst = &gis[(t + 1) & 1][0];
      __builtin_amdgcn_global_load_lds(
          (const __attribute__((address_space(1))) void*)(src + tid * 8),
          (__attribute__((address_space(3))) void*)(dst + tid * 8), 16, 0, 0);
      if (tid < 128)
        __builtin_amdgcn_global_load_lds(
            (const __attribute__((address_space(1))) void*)(src + (512 + tid) * 8),
            (__attribute__((address_space(3))) void*)(dst + (512 + tid) * 8), 16, 0, 0);
    }

    if (t < crow){
      const u16* gr = &gis[t & 1][0] + grow * 640;
      #pragma unroll
      for (int k = 0; k < 4; ++k){
        int d = lane + 64 * k;
        if (d < 200){
          float i0 = bf2f(gr[d]);
          float i1 = bf2f(gr[200 + d]);
          float i2 = bf2f(gr[400 + d]);
          float g0 = ghs[grow][d] + bhs[d];
          float g1 = ghs[grow][200 + d] + bhs[200 + d];
          float g2 = ghs[grow][400 + d] + bhs[400 + d];
          float e0 = __expf(-(i0 + g0));
          float r_ = __builtin_amdgcn_rcpf(1.f + e0);
          float e1 = __expf(-(i1 + g1));
          float z  = __builtin_amdgcn_rcpf(1.f + e1);
          float xn = i2 + r_ * g2;
          float e2 = __expf(2.f * xn);
          float n_ = 1.f - 2.f * __builtin_amdgcn_rcpf(e2 + 1.f);
          float hn = (1.f - z) * n_ + z * hf[grow * 200 + d];
          hf[grow * 200 + d] = hn;
          hbf[(grow * 256 + d) ^ (grow << 3)] = f2bf(hn);
        }
      }
    }
    __builtin_amdgcn_sched_barrier(0);
    asm volatile("s_waitcnt lgkmcnt(0)" ::: "memory");
    __builtin_amdgcn_sched_barrier(0);
    __builtin_amdgcn_s_barrier();
    __builtin_amdgcn_sched_barrier(0);
  }

  for (int i = tid; i < 1600; i += 512){
    int row = i / 200, d = i - row * 200;
    hout[(size_t)(rb + row) * 200 + d] = hf[row * 200 + d];
  }
}

// ---------------- fused: gh = GRU(q_rel, ph) and A_big = aligned_sub * gh ------------
__global__ __launch_bounds__(256) void gru2_abig(const float* __restrict__ gi,
                                                 const float* __restrict__ gg,
                                                 const float* __restrict__ hprev,
                                                 const float* __restrict__ al32,
                                                 const int* __restrict__ trip,
                                                 u16* __restrict__ abig){
  int i = blockIdx.x * 256 + threadIdx.x;
  if (i < 2048 * 256){
    int b = i >> 8, c = i & 255;
    u16 v = 0;
    if (c < 200){
      float i0 = gi[b * 600 + c], i1 = gi[b * 600 + 200 + c], i2 = gi[b * 600 + 400 + c];
      float g0 = gg[b * 600 + c], g1 = gg[b * 600 + 200 + c], g2 = gg[b * 600 + 400 + c];
      float r = sigf(i0 + g0);
      float z = sigf(i1 + g1);
      float n = tanhf(i2 + r * g2);
      float gh = (1.f - z) * n + z * hprev[b * 200 + c];
      int sub = trip[b * 3 + 0];
      v = f2bf(al32[(size_t)sub * 200 + c] * gh);
    }
    abig[i] = v;
  }
}

// =====================================================================================
extern "C" void kernel_launch(void* const* d_in, const int* in_sizes, int n_in,
                              void* d_out, int out_size, void* d_ws, size_t ws_size,
                              hipStream_t stream)
{
  (void)in_sizes; (void)n_in; (void)out_size; (void)ws_size;
  const float* pre_emb = (const float*)d_in[0];
  const float* r_emb   = (const float*)d_in[1];
  const int*   trip    = (const int*)d_in[2];
  const float* part    = (const float*)d_in[3];
  const int*   cur_ts  = (const int*)d_in[4];
  const float* Wmap1 = (const float*)d_in[5];   const float* bmap1 = (const float*)d_in[6];
  const float* Wmap2 = (const float*)d_in[7];   const float* bmap2 = (const float*)d_in[8];
  const float* Wattn = (const float*)d_in[9];   const float* battn = (const float*)d_in[10];
  const float* Wih   = (const float*)d_in[11];  const float* Whh   = (const float*)d_in[12];
  const float* bih   = (const float*)d_in[13];  const float* bhh   = (const float*)d_in[14];
  const float* Wh1   = (const float*)d_in[15];  const float* bh1   = (const float*)d_in[16];
  const float* Wh2   = (const float*)d_in[17];  const float* bh2   = (const float*)d_in[18];
  const float* Wal   = (const float*)d_in[19];  const float* bal   = (const float*)d_in[20];
  float* out = (float*)d_out;

  char* wsb = (char*)d_ws;
  size_t off = 0;
  auto alloc = [&](size_t bytes) -> void* {
    void* p = wsb + off;
    off = (off + bytes + 255) & ~(size_t)255;
    return p;
  };
  u16* re_bf     = (u16*)alloc((size_t)512 * 256 * 2);
  u16* wmap1_bf  = (u16*)alloc((size_t)512 * 256 * 2);
  u16* wmap2_bf  = (u16*)alloc((size_t)256 * 448 * 2);
  u16* wattn_bf  = (u16*)alloc((size_t)256 * 256 * 2);
  u16* wih_bf    = (u16*)alloc((size_t)640 * 256 * 2);
  u16* whh_bf    = (u16*)alloc((size_t)640 * 256 * 2);
  u16* wh1_bf    = (u16*)alloc((size_t)256 * 256 * 2);
  u16* wh2_bf    = (u16*)alloc((size_t)256 * 256 * 2);
  u16* wal_bf    = (u16*)alloc((size_t)256 * 256 * 2);
  u16* pre_bf    = (u16*)alloc((size_t)10112 * 256 * 2);
  u16* hidden_bf = (u16*)alloc((size_t)512 * 512 * 2);
  u16* mrel_bf   = (u16*)alloc((size_t)512 * 256 * 2);
  u16* m2t_bf    = (u16*)alloc((size_t)640 * 512 * 2);
  u16* qrel_bf   = (u16*)alloc((size_t)2048 * 256 * 2);
  u16* qa_bf     = (u16*)alloc((size_t)2048 * 256 * 2);
  u16* ph1_bf    = (u16*)alloc((size_t)2048 * 256 * 2);
  u16* ph_bf     = (u16*)alloc((size_t)2048 * 256 * 2);
  u16* abig_bf   = (u16*)alloc((size_t)2048 * 256 * 2);
  u16* gi_all    = (u16*)alloc((size_t)65536 * 640 * 2);
  float* mrel32 = (float*)alloc((size_t)460 * 200 * 4);
  float* base32 = (float*)alloc((size_t)2048 * 460 * 4);
  float* qrel32 = (float*)alloc((size_t)2048 * 200 * 4);
  float* hout   = (float*)alloc((size_t)2048 * 200 * 4);
  float* ph32   = (float*)alloc((size_t)2048 * 200 * 4);
  int* pairs    = (int*)alloc((size_t)65536 * 4);
  int* cntt     = (int*)alloc((size_t)64 * 4);
  int* toff     = (int*)alloc((size_t)64 * 4);
  // U region: a_comp (pre-scan) aliases post-scan fp32/bf16 buffers (no temporal overlap)
  char* U = (char*)alloc((size_t)40200 * 512 * 2);   // 41.2 MB (pad covers tile overreach)
  u16*   a_comp = (u16*)U;                           // ~31.7K rows x 512 bf16
  float* gi2    = (float*)(U);                       // 2048x600 f32 (4.9 MB)
  float* ghg    = (float*)(U + (size_t)5  * 1024 * 1024);
  float* al32   = (float*)(U + (size_t)12 * 1024 * 1024);  // 10000x200 f32 (8 MB)
  u16*   al_bf  = (u16*)  (U + (size_t)21 * 1024 * 1024);  // 10000x256 bf16 (5.2 MB)

  cntt_k<<<32, 256, 0, stream>>>(cur_ts, cntt, out);
  toff_k<<<1, 32, 0, stream>>>(cntt, toff);
  fill_pairs_t<<<32, 256, 0, stream>>>(cur_ts, toff, pairs);

  CvtTab tab;
  tab.t[0] = { r_emb,   re_bf,    460, 200,   512, 256 };
  tab.t[1] = { Wmap1,   wmap1_bf, 400, 200,   512, 256 };
  tab.t[2] = { Wmap2,   wmap2_bf, 200, 400,   256, 448 };
  tab.t[3] = { Wattn,   wattn_bf, 200, 200,   256, 256 };
  tab.t[4] = { Wih,     wih_bf,   600, 200,   640, 256 };
  tab.t[5] = { Whh,     whh_bf,   600, 200,   640, 256 };
  tab.t[6] = { Wh1,     wh1_bf,   200, 200,   256, 256 };
  tab.t[7] = { Wh2,     wh2_bf,   200, 200,   256, 256 };
  tab.t[8] = { Wal,     wal_bf,   200, 200,   256, 256 };
  tab.t[9] = { pre_emb, pre_bf, 10000, 200, 10112, 256 };
  cvt_all<<<dim3(512, 10), 256, 0, stream>>>(tab);

  gemm_bt<0,0,7><<<dim3(4, 4), 256, 0, stream>>>(re_bf, 256, wmap1_bf, 256, 200, 460, 400,
      bmap1, nullptr, hidden_bf, 512, nullptr, nullptr, nullptr, nullptr, nullptr,
      nullptr, nullptr, nullptr, nullptr, nullptr, 0, 0);
  gemm_bt<0,0,13><<<dim3(2, 4), 256, 0, stream>>>(hidden_bf, 512, wmap2_bf, 448, 400, 460, 200,
      bmap2, mrel32, mrel_bf, 256, nullptr, nullptr, nullptr, nullptr, nullptr,
      nullptr, nullptr, nullptr, nullptr, nullptr, 0, 0);
  gather_qrel<<<2048, 256, 0, stream>>>(mrel_bf, mrel32, trip, qrel_bf, qrel32);

  // z-batched: qa = qrel@Wattn^T + b  ||  ph1 = qrel@Wh1^T + b
  gemm_bt<0,0,7><<<dim3(2, 16, 2), 256, 0, stream>>>(qrel_bf, 256, wattn_bf, 256, 200, 2048, 200,
      battn, nullptr, qa_bf, 256, nullptr, nullptr, nullptr, nullptr, nullptr,
      qrel_bf, wh1_bf, bh1, nullptr, ph1_bf, 2048, 256);

  // z-batched: base = qa@mrel^T (fp32)  ||  M2T = Wih@mrel^T (bf16, 600x460 ld 512)
  gemm_bt<0,0,7><<<dim3(4, 16, 2), 256, 0, stream>>>(qa_bf, 256, mrel_bf, 256, 200, 2048, 460,
      nullptr, base32, nullptr, 0, nullptr, nullptr, nullptr, nullptr, nullptr,
      wih_bf, mrel_bf, nullptr, nullptr, m2t_bf, 600, 512);

  // compacted softmax -> compacted gi GEMM (row-indirect out)
  softmax_c<<<2048, 256, 0, stream>>>(part, base32, pairs, toff, a_comp);
  gemm_bt<3,0,15><<<dim3(5, 313), 256, 0, stream>>>(a_comp, 512, m2t_bf, 512, 460, 0, 600,
      bih, nullptr, gi_all, 640, nullptr, nullptr, pairs, nullptr, toff,
      nullptr, nullptr, nullptr, nullptr, nullptr, 0, 0);

  gru_scan3<<<256, 512, 0, stream>>>(gi_all, whh_bf, bhh, cur_ts, hout);

  // predicted_hist + fused match_loss (hout ready)
  gemm_bt<1,0,7><<<dim3(2, 16), 256, 0, stream>>>(ph1_bf, 256, wh2_bf, 256, 200, 2048, 200,
      bh2, ph32, ph_bf, 256, qrel32, hout, nullptr, out, nullptr,
      nullptr, nullptr, nullptr, nullptr, nullptr, 0, 0);

  // z-batched: gi2 = qrel@Wih^T + bih  ||  ghg = ph@Whh^T + bhh
  gemm_bt<0,0,7><<<dim3(5, 16, 2), 256, 0, stream>>>(qrel_bf, 256, wih_bf, 256, 200, 2048, 600,
      bih, gi2, nullptr, 0, nullptr, nullptr, nullptr, nullptr, nullptr,
      ph_bf, whh_bf, bhh, ghg, nullptr, 2048, 0);

  gemm_bt<0,0,7><<<dim3(2, 79), 256, 0, stream>>>(pre_bf, 256, wal_bf, 256, 200, 10000, 200,
      bal, al32, al_bf, 256, nullptr, nullptr, nullptr, nullptr, nullptr,
      nullptr, nullptr, nullptr, nullptr, nullptr, 0, 0);

  gru2_abig<<<2048, 256, 0, stream>>>(gi2, ghg, ph32, al32, trip, abig_bf);

  gemm_bt<2,1,7><<<dim3(79, 16), 256, 0, stream>>>(abig_bf, 256, al_bf, 256, 200, 2048, 10000,
      nullptr, out, nullptr, 0, nullptr, nullptr, trip, out + 1, nullptr,
      nullptr, nullptr, nullptr, nullptr, nullptr, 0, 0);
}

// Round 16
// 336.398 us; speedup vs baseline: 1.4010x; 1.4010x over previous
//
#include <hip/hip_runtime.h>
#include <cstdint>
#include <cstddef>

typedef unsigned short u16;
typedef __attribute__((ext_vector_type(8))) short short8;
typedef __attribute__((ext_vector_type(4))) float f32x4;

__device__ __forceinline__ f32x4 mfma16(short8 a, short8 b, f32x4 c){
  return __builtin_amdgcn_mfma_f32_16x16x32_bf16(a, b, c, 0, 0, 0);
}
__device__ __forceinline__ float bf2f(u16 u){
  unsigned v = ((unsigned)u) << 16; float f; __builtin_memcpy(&f, &v, 4); return f;
}
__device__ __forceinline__ u16 f2bf(float f){
  unsigned u; __builtin_memcpy(&u, &f, 4);
  u += 0x7FFFu + ((u >> 16) & 1u);
  return (u16)(u >> 16);
}
__device__ __forceinline__ float sigf(float x){ return 1.f / (1.f + __expf(-x)); }

// ---------------- fp32 -> zero-padded bf16 conversion ----------------
struct CvtD { const float* s; u16* d; int M, K, Mp, Kp; };
struct CvtTab { CvtD t[10]; };

__global__ void cvt_all(CvtTab tab){
  CvtD de = tab.t[blockIdx.y];
  int total = de.Mp * de.Kp;
  for (int i = blockIdx.x * blockDim.x + threadIdx.x; i < total; i += gridDim.x * blockDim.x){
    int r = i / de.Kp, c = i - r * de.Kp;
    float v = (r < de.M && c < de.K) ? de.s[(size_t)r * de.K + c] : 0.f;
    de.d[i] = f2bf(v);
  }
}

// q_rel gather
__global__ void gather_qrel(const u16* __restrict__ mbf, const float* __restrict__ m32,
                            const int* __restrict__ trip, u16* __restrict__ qbf,
                            float* __restrict__ q32){
  int i = blockIdx.x * blockDim.x + threadIdx.x;
  if (i < 2048 * 256){
    int b = i >> 8, c = i & 255;
    int rel = trip[b * 3 + 1];
    qbf[i] = mbf[rel * 256 + c];
    if (c < 200) q32[b * 200 + c] = m32[rel * 200 + c];
  }
}

// ---------------- compaction: t-major pair list of (t,b) with t < cur_ts[b] ---------
__global__ void cntt_k(const int* __restrict__ cur_ts, int* __restrict__ cntt,
                       float* __restrict__ out0){
  int t = blockIdx.x;
  __shared__ int psum[256];
  int tid = threadIdx.x, s = 0;
  #pragma unroll
  for (int k = 0; k < 8; ++k) s += (cur_ts[tid * 8 + k] > t) ? 1 : 0;
  psum[tid] = s; __syncthreads();
  for (int st = 128; st > 0; st >>= 1){
    if (tid < st) psum[tid] += psum[tid + st];
    __syncthreads();
  }
  if (tid == 0){
    cntt[t] = psum[0];
    if (t == 0){ out0[0] = 0.f; out0[1] = 0.f; }
  }
}
__global__ void toff_k(const int* __restrict__ cntt, int* __restrict__ toff){
  if (threadIdx.x == 0){
    int run = 0;
    for (int t = 0; t < 32; ++t){ toff[t] = run; run += cntt[t]; }
    toff[32] = run;
  }
}
__global__ void fill_pairs_t(const int* __restrict__ cur_ts, const int* __restrict__ toff,
                             int* __restrict__ pairs){
  int t = blockIdx.x;
  __shared__ int psum[256];
  int tid = threadIdx.x;
  int loc[8]; int tsum = 0;
  #pragma unroll
  for (int k = 0; k < 8; ++k){ loc[k] = (cur_ts[tid * 8 + k] > t) ? 1 : 0; tsum += loc[k]; }
  psum[tid] = tsum; __syncthreads();
  for (int st = 1; st < 256; st <<= 1){
    int v = (tid >= st) ? psum[tid - st] : 0;
    __syncthreads();
    psum[tid] += v;
    __syncthreads();
  }
  int run = psum[tid] - tsum + toff[t];
  #pragma unroll
  for (int k = 0; k < 8; ++k)
    if (loc[k]){ pairs[run] = t * 2048 + tid * 8 + k; ++run; }
}

// ---------------- generic MFMA GEMM: BK=32, 3-buffer depth-2, SINGLE barrier/step ----
// GROUP 0: natural 2D mapping.  GROUP 1: mx-major ORDERING (temporal B-panel reuse),
// NO xcd-deinterleave (blockIdx->XCD mapping is undefined; A/B vs R14 isolates it).
// MODE 0: fp32/bf16 C (z-batchable incl. per-z Mreal/ldc16).  MODE 1: ph + match_loss.
// MODE 2: score epilogue.  MODE 3: compacted gi (row-indirect out via pairs).
template<int MODE, int GROUP>
__global__ __launch_bounds__(256) void gemm_bt(
    const u16* A, int lda,
    const u16* B, int ldb,
    int K, int Mreal, int Nreal,
    const float* bias,
    float* C32,
    u16* C16, int ldc16,
    const float* __restrict__ extra,
    const float* __restrict__ extra2,
    const int* __restrict__ trip,
    float* __restrict__ loss,
    const int* __restrict__ tcnt,
    const u16* A2, const u16* B2, const float* bias2, float* C32b, u16* C16b,
    int Mreal2, int ldc16b)
{
  __shared__ u16 AB[3][2][128 * 32];   // 48 KB
  __shared__ float red[256];
  const int tid = threadIdx.x;
  const int wave = tid >> 6, lane = tid & 63;

  if (MODE == 0 && blockIdx.z){
    A = A2; B = B2; bias = bias2; C32 = C32b; C16 = C16b;
    Mreal = Mreal2; ldc16 = ldc16b;
  }

  int mx, my;
  if (GROUP == 0){
    my = blockIdx.y; mx = blockIdx.x;
  } else {
    const int gx = gridDim.x, gy = gridDim.y;
    int orig = blockIdx.y * gx + blockIdx.x;
    mx = orig / gy; my = orig - mx * gy;
  }

  const int m0 = my * 128, n0 = mx * 128;

  int Mg_ = Mreal;
  if (MODE == 3) Mg_ = tcnt[32];
  if (m0 >= Mg_) return;

  const int wm = (wave >> 1) * 64, wn = (wave & 1) * 64;
  const int srow = lane >> 2;
  const int scol = (((lane & 3) ^ (srow & 3)) * 8);
  const int fr = lane & 15, fkg = lane >> 4;
  const int slot = (fkg ^ (fr & 3)) * 8;

  f32x4 acc[4][4];
  #pragma unroll
  for (int i = 0; i < 4; ++i)
    #pragma unroll
    for (int j = 0; j < 4; ++j) acc[i][j] = (f32x4){0.f, 0.f, 0.f, 0.f};

  const int kT = (K + 31) >> 5;

  auto STAGE = [&](int kt, int p){
    #pragma unroll
    for (int i = 0; i < 2; ++i){
      int ch = wave * 2 + i;
      const u16* ga = A + (size_t)(m0 + ch * 16 + srow) * lda + kt * 32 + scol;
      __builtin_amdgcn_global_load_lds((const __attribute__((address_space(1))) void*)ga,
          (__attribute__((address_space(3))) void*)(&AB[p][0][0] + ch * 512), 16, 0, 0);
      const u16* gb = B + (size_t)(n0 + ch * 16 + srow) * ldb + kt * 32 + scol;
      __builtin_amdgcn_global_load_lds((const __attribute__((address_space(1))) void*)gb,
          (__attribute__((address_space(3))) void*)(&AB[p][1][0] + ch * 512), 16, 0, 0);
    }
  };

  STAGE(0, 0);
  if (kT > 1) STAGE(1, 1);
  for (int kt = 0; kt < kT; ++kt){
    const int p = kt % 3;
    if (kt + 1 < kT){
      __builtin_amdgcn_sched_barrier(0);
      asm volatile("s_waitcnt vmcnt(4)" ::: "memory");   // tile kt's 4 loads landed
    } else {
      __builtin_amdgcn_sched_barrier(0);
      asm volatile("s_waitcnt vmcnt(0)" ::: "memory");
    }
    __builtin_amdgcn_sched_barrier(0);
    __builtin_amdgcn_s_barrier();                        // single barrier per K-step
    __builtin_amdgcn_sched_barrier(0);

    if (kt + 2 < kT) STAGE(kt + 2, (kt + 2) % 3);

    short8 av[4], bv[4];
    #pragma unroll
    for (int i = 0; i < 4; ++i){
      av[i] = *(const short8*)(&AB[p][0][0] + (wm + i * 16 + fr) * 32 + slot);
      bv[i] = *(const short8*)(&AB[p][1][0] + (wn + i * 16 + fr) * 32 + slot);
    }
    #pragma unroll
    for (int i = 0; i < 4; ++i)
      #pragma unroll
      for (int j = 0; j < 4; ++j)
        acc[i][j] = mfma16(av[i], bv[j], acc[i][j]);
  }

  if (MODE == 2){
    float lsum = 0.f;
    #pragma unroll
    for (int i = 0; i < 4; ++i){
      #pragma unroll
      for (int r = 0; r < 4; ++r){
        int row = m0 + wm + i * 16 + (lane >> 4) * 4 + r;
        int tcol = trip[row * 3 + 2];
        #pragma unroll
        for (int j = 0; j < 4; ++j){
          int col = n0 + wn + j * 16 + fr;
          if (col < Nreal){
            float v = acc[i][j][r];
            float e = __expf(-fabsf(v));
            float inv = __builtin_amdgcn_rcpf(1.f + e);
            C32[2 + (size_t)row * Nreal + col] = (v >= 0.f) ? inv : e * inv;
            float x = (tcol == col) ? v : -v;
            lsum += fminf(x, 0.f) - __logf(1.f + e);
          }
        }
      }
    }
    red[tid] = lsum;
    __syncthreads();
    for (int s = 128; s > 0; s >>= 1){
      if (tid < s) red[tid] += red[tid + s];
      __syncthreads();
    }
    if (tid == 0) atomicAdd(loss, -red[0] * (1.f / 20480000.f));
    return;
  }

  if (MODE == 3){
    #pragma unroll
    for (int i = 0; i < 4; ++i){
      #pragma unroll
      for (int r = 0; r < 4; ++r){
        int row = m0 + wm + i * 16 + (lane >> 4) * 4 + r;
        if (row < Mg_){
          int orow = trip[row];            // pairs[]: t*2048+b
          #pragma unroll
          for (int j = 0; j < 4; ++j){
            int col = n0 + wn + j * 16 + fr;
            if (col < Nreal)
              C16[(size_t)orow * ldc16 + col] = f2bf(acc[i][j][r] + bias[col]);
          }
        }
      }
    }
    return;
  }

  if (MODE == 1){
    float lsum = 0.f;
    #pragma unroll
    for (int i = 0; i < 4; ++i){
      #pragma unroll
      for (int j = 0; j < 4; ++j){
        int col = n0 + wn + j * 16 + fr;
        float bvl = (col < Nreal) ? bias[col] : 0.f;
        #pragma unroll
        for (int r = 0; r < 4; ++r){
          int row = m0 + wm + i * 16 + (lane >> 4) * 4 + r;
          if (col < Nreal){
            float pv = 0.1f * (acc[i][j][r] + bvl) + extra[(size_t)row * Nreal + col];
            C32[(size_t)row * Nreal + col] = pv;
            C16[(size_t)row * ldc16 + col] = f2bf(pv);
            float d = pv - extra2[(size_t)row * Nreal + col];
            lsum += d * d;
          } else {
            C16[(size_t)row * ldc16 + col] = 0;
          }
        }
      }
    }
    red[tid] = lsum;
    __syncthreads();
    for (int s = 128; s > 0; s >>= 1){
      if (tid < s) red[tid] += red[tid + s];
      __syncthreads();
    }
    if (tid == 0) atomicAdd(loss, red[0] * (1.f / 409600.f));
    return;
  }

  #pragma unroll
  for (int i = 0; i < 4; ++i){
    #pragma unroll
    for (int j = 0; j < 4; ++j){
      int col = n0 + wn + j * 16 + fr;
      float bvl = 0.f;
      if (bias && col < Nreal) bvl = bias[col];
      #pragma unroll
      for (int r = 0; r < 4; ++r){
        int row = m0 + wm + i * 16 + (lane >> 4) * 4 + r;
        float v = acc[i][j][r] + bvl;
        if (C32 && row < Mreal && col < Nreal) C32[(size_t)row * Nreal + col] = v;
        if (C16) C16[(size_t)row * ldc16 + col] =
            (row < Mreal && col < Nreal) ? f2bf(v) : (u16)0;
      }
    }
  }
}

// ---------------- compacted masked softmax over R=460 (single dispatch) -------------
__global__ __launch_bounds__(256) void softmax_c(
    const float* __restrict__ part, const float* __restrict__ base,
    const int* __restrict__ pairs, const int* __restrict__ toff,
    u16* __restrict__ aout)
{
  int wave = threadIdx.x >> 6, lane = threadIdx.x & 63;
  int hi = toff[32];
  for (int j = blockIdx.x * 4 + wave; j < hi; j += gridDim.x * 4){
    int p = pairs[j];
    int b = p & 2047, t = p >> 11;
    const float* pr = part + (size_t)b * 14720 + t * 460;
    const float* br = base + (size_t)b * 460;
    int r0 = lane * 8;
    float vals[8];
    if (lane < 57){
      float4 pa = *(const float4*)(pr + r0);
      float4 pb = *(const float4*)(pr + r0 + 4);
      float4 ba = *(const float4*)(br + r0);
      float4 bb = *(const float4*)(br + r0 + 4);
      float pv[8] = {pa.x, pa.y, pa.z, pa.w, pb.x, pb.y, pb.z, pb.w};
      float bw[8] = {ba.x, ba.y, ba.z, ba.w, bb.x, bb.y, bb.z, bb.w};
      #pragma unroll
      for (int u = 0; u < 8; ++u){
        float a = pv[u] * bw[u];
        bool valid = (r0 + u) < 460;
        vals[u] = (!valid) ? -__builtin_inff() : ((a == 0.f) ? -1000000000.0f : a);
      }
    } else {
      #pragma unroll
      for (int u = 0; u < 8; ++u){
        int r = r0 + u;
        if (r < 460){
          float a = pr[r] * br[r];
          vals[u] = (a == 0.f) ? -1000000000.0f : a;
        } else vals[u] = -__builtin_inff();
      }
    }
    float m = vals[0];
    #pragma unroll
    for (int u = 1; u < 8; ++u) m = fmaxf(m, vals[u]);
    #pragma unroll
    for (int s = 1; s < 64; s <<= 1) m = fmaxf(m, __shfl_xor(m, s));
    float e[8]; float sum = 0.f;
    #pragma unroll
    for (int u = 0; u < 8; ++u){
      float x = vals[u];
      float ev = (x == -__builtin_inff()) ? 0.f : __expf(x - m);
      e[u] = ev; sum += ev;
    }
    #pragma unroll
    for (int s = 1; s < 64; s <<= 1) sum += __shfl_xor(sum, s);
    float inv = __builtin_amdgcn_rcpf(sum);
    union { u16 o[8]; uint4 v; } pk;
    #pragma unroll
    for (int u = 0; u < 8; ++u) pk.o[u] = f2bf(e[u] * inv);
    *(uint4*)(aout + (size_t)j * 512 + r0) = pk.v;
  }
}

// ---------------- GRU recurrence v3: 256 blocks x 8 rows x 8 waves ------------------
__global__ __launch_bounds__(512, 2) void gru_scan3(
    const u16* __restrict__ gi_all,
    const u16* __restrict__ Whh,
    const float* __restrict__ bhh,
    const int* __restrict__ cur_ts,
    float* __restrict__ hout)
{
  __shared__ u16 hbf[16 * 256];
  __shared__ float hf[8 * 200];
  __shared__ float ghs[8][648];
  __shared__ u16 gis[2][8 * 640];
  __shared__ float bhs[600];
  __shared__ int cts[8];
  const int tid = threadIdx.x, wave = tid >> 6, lane = tid & 63;
  const int rb = blockIdx.x * 8;
  const int fr = lane & 15, fkg = lane >> 4;
  const int fk = fkg * 8;

  for (int i = tid; i < 16 * 256; i += 512) hbf[i] = 0;
  for (int i = tid; i < 8 * 200; i += 512) hf[i] = 0.f;
  for (int i = tid; i < 600; i += 512) bhs[i] = bhh[i];
  if (tid < 8) cts[tid] = cur_ts[rb + tid];
  __syncthreads();
  int Trun = 0;
  #pragma unroll
  for (int r = 0; r < 8; ++r) Trun = max(Trun, cts[r]);

  short8 wb[5][7];
  #pragma unroll
  for (int f = 0; f < 5; ++f)
    #pragma unroll
    for (int ks = 0; ks < 7; ++ks)
      wb[f][ks] = *(const short8*)(Whh + (size_t)(wave * 80 + f * 16 + fr) * 256 + ks * 32 + fk);

  if (Trun > 0){
    const u16* src = gi_all + (size_t)rb * 640;
    __builtin_amdgcn_global_load_lds(
        (const __attribute__((address_space(1))) void*)(src + tid * 8),
        (__attribute__((address_space(3))) void*)(&gis[0][0] + tid * 8), 16, 0, 0);
    if (tid < 128)
      __builtin_amdgcn_global_load_lds(
          (const __attribute__((address_space(1))) void*)(src + (512 + tid) * 8),
          (__attribute__((address_space(3))) void*)(&gis[0][0] + (512 + tid) * 8), 16, 0, 0);
  }
  __syncthreads();

  const int grow = wave;
  const int crow = (Trun > 0) ? cts[grow] : 0;

  for (int t = 0; t < Trun; ++t){
    f32x4 acc[5];
    #pragma unroll
    for (int f = 0; f < 5; ++f) acc[f] = (f32x4){0.f, 0.f, 0.f, 0.f};
    #pragma unroll
    for (int ks = 0; ks < 7; ++ks){
      short8 av = *(const short8*)(hbf + ((fr * 256 + ks * 32 + fk) ^ ((fr & 7) << 3)));
      #pragma unroll
      for (int f = 0; f < 5; ++f)
        acc[f] = mfma16(av, wb[f][ks], acc[f]);
    }
    if (fkg < 2){
      #pragma unroll
      for (int f = 0; f < 5; ++f){
        int col = wave * 80 + f * 16 + fr;
        #pragma unroll
        for (int r = 0; r < 4; ++r)
          ghs[fkg * 4 + r][col] = acc[f][r];
      }
    }
    __builtin_amdgcn_sched_barrier(0);
    asm volatile("s_waitcnt vmcnt(0) lgkmcnt(0)" ::: "memory");
    __builtin_amdgcn_sched_barrier(0);
    __builtin_amdgcn_s_barrier();
    __builtin_amdgcn_sched_barrier(0);

    if (t + 1 < Trun){
      const u16* src = gi_all + ((size_t)(t + 1) * 2048 + rb) * 640;
      u16* dst = &gis[(t + 1) & 1][0];
      __builtin_amdgcn_global_load_lds(
          (const __attribute__((address_space(1))) void*)(src + tid * 8),
          (__attribute__((address_space(3))) void*)(dst + tid * 8), 16, 0, 0);
      if (tid < 128)
        __builtin_amdgcn_global_load_lds(
            (const __attribute__((address_space(1))) void*)(src + (512 + tid) * 8),
            (__attribute__((address_space(3))) void*)(dst + (512 + tid) * 8), 16, 0, 0);
    }

    if (t < crow){
      const u16* gr = &gis[t & 1][0] + grow * 640;
      #pragma unroll
      for (int k = 0; k < 4; ++k){
        int d = lane + 64 * k;
        if (d < 200){
          float i0 = bf2f(gr[d]);
          float i1 = bf2f(gr[200 + d]);
          float i2 = bf2f(gr[400 + d]);
          float g0 = ghs[grow][d] + bhs[d];
          float g1 = ghs[grow][200 + d] + bhs[200 + d];
          float g2 = ghs[grow][400 + d] + bhs[400 + d];
          float e0 = __expf(-(i0 + g0));
          float r_ = __builtin_amdgcn_rcpf(1.f + e0);
          float e1 = __expf(-(i1 + g1));
          float z  = __builtin_amdgcn_rcpf(1.f + e1);
          float xn = i2 + r_ * g2;
          float e2 = __expf(2.f * xn);
          float n_ = 1.f - 2.f * __builtin_amdgcn_rcpf(e2 + 1.f);
          float hn = (1.f - z) * n_ + z * hf[grow * 200 + d];
          hf[grow * 200 + d] = hn;
          hbf[(grow * 256 + d) ^ (grow << 3)] = f2bf(hn);
        }
      }
    }
    __builtin_amdgcn_sched_barrier(0);
    asm volatile("s_waitcnt lgkmcnt(0)" ::: "memory");
    __builtin_amdgcn_sched_barrier(0);
    __builtin_amdgcn_s_barrier();
    __builtin_amdgcn_sched_barrier(0);
  }

  for (int i = tid; i < 1600; i += 512){
    int row = i / 200, d = i - row * 200;
    hout[(size_t)(rb + row) * 200 + d] = hf[row * 200 + d];
  }
}

// ---------------- fused: gh = GRU(q_rel, ph) and A_big = aligned_sub * gh ------------
__global__ __launch_bounds__(256) void gru2_abig(const float* __restrict__ gi,
                                                 const float* __restrict__ gg,
                                                 const float* __restrict__ hprev,
                                                 const float* __restrict__ al32,
                                                 const int* __restrict__ trip,
                                                 u16* __restrict__ abig){
  int i = blockIdx.x * 256 + threadIdx.x;
  if (i < 2048 * 256){
    int b = i >> 8, c = i & 255;
    u16 v = 0;
    if (c < 200){
      float i0 = gi[b * 600 + c], i1 = gi[b * 600 + 200 + c], i2 = gi[b * 600 + 400 + c];
      float g0 = gg[b * 600 + c], g1 = gg[b * 600 + 200 + c], g2 = gg[b * 600 + 400 + c];
      float r = sigf(i0 + g0);
      float z = sigf(i1 + g1);
      float n = tanhf(i2 + r * g2);
      float gh = (1.f - z) * n + z * hprev[b * 200 + c];
      int sub = trip[b * 3 + 0];
      v = f2bf(al32[(size_t)sub * 200 + c] * gh);
    }
    abig[i] = v;
  }
}

// =====================================================================================
extern "C" void kernel_launch(void* const* d_in, const int* in_sizes, int n_in,
                              void* d_out, int out_size, void* d_ws, size_t ws_size,
                              hipStream_t stream)
{
  (void)in_sizes; (void)n_in; (void)out_size; (void)ws_size;
  const float* pre_emb = (const float*)d_in[0];
  const float* r_emb   = (const float*)d_in[1];
  const int*   trip    = (const int*)d_in[2];
  const float* part    = (const float*)d_in[3];
  const int*   cur_ts  = (const int*)d_in[4];
  const float* Wmap1 = (const float*)d_in[5];   const float* bmap1 = (const float*)d_in[6];
  const float* Wmap2 = (const float*)d_in[7];   const float* bmap2 = (const float*)d_in[8];
  const float* Wattn = (const float*)d_in[9];   const float* battn = (const float*)d_in[10];
  const float* Wih   = (const float*)d_in[11];  const float* Whh   = (const float*)d_in[12];
  const float* bih   = (const float*)d_in[13];  const float* bhh   = (const float*)d_in[14];
  const float* Wh1   = (const float*)d_in[15];  const float* bh1   = (const float*)d_in[16];
  const float* Wh2   = (const float*)d_in[17];  const float* bh2   = (const float*)d_in[18];
  const float* Wal   = (const float*)d_in[19];  const float* bal   = (const float*)d_in[20];
  float* out = (float*)d_out;

  char* wsb = (char*)d_ws;
  size_t off = 0;
  auto alloc = [&](size_t bytes) -> void* {
    void* p = wsb + off;
    off = (off + bytes + 255) & ~(size_t)255;
    return p;
  };
  u16* re_bf     = (u16*)alloc((size_t)512 * 256 * 2);
  u16* wmap1_bf  = (u16*)alloc((size_t)512 * 256 * 2);
  u16* wmap2_bf  = (u16*)alloc((size_t)256 * 448 * 2);
  u16* wattn_bf  = (u16*)alloc((size_t)256 * 256 * 2);
  u16* wih_bf    = (u16*)alloc((size_t)640 * 256 * 2);
  u16* whh_bf    = (u16*)alloc((size_t)640 * 256 * 2);
  u16* wh1_bf    = (u16*)alloc((size_t)256 * 256 * 2);
  u16* wh2_bf    = (u16*)alloc((size_t)256 * 256 * 2);
  u16* wal_bf    = (u16*)alloc((size_t)256 * 256 * 2);
  u16* pre_bf    = (u16*)alloc((size_t)10112 * 256 * 2);
  u16* hidden_bf = (u16*)alloc((size_t)512 * 512 * 2);
  u16* mrel_bf   = (u16*)alloc((size_t)512 * 256 * 2);
  u16* m2t_bf    = (u16*)alloc((size_t)640 * 512 * 2);
  u16* qrel_bf   = (u16*)alloc((size_t)2048 * 256 * 2);
  u16* qa_bf     = (u16*)alloc((size_t)2048 * 256 * 2);
  u16* ph1_bf    = (u16*)alloc((size_t)2048 * 256 * 2);
  u16* ph_bf     = (u16*)alloc((size_t)2048 * 256 * 2);
  u16* abig_bf   = (u16*)alloc((size_t)2048 * 256 * 2);
  u16* gi_all    = (u16*)alloc((size_t)65536 * 640 * 2);
  float* mrel32 = (float*)alloc((size_t)460 * 200 * 4);
  float* base32 = (float*)alloc((size_t)2048 * 460 * 4);
  float* qrel32 = (float*)alloc((size_t)2048 * 200 * 4);
  float* hout   = (float*)alloc((size_t)2048 * 200 * 4);
  float* ph32   = (float*)alloc((size_t)2048 * 200 * 4);
  int* pairs    = (int*)alloc((size_t)65536 * 4);
  int* cntt     = (int*)alloc((size_t)64 * 4);
  int* toff     = (int*)alloc((size_t)64 * 4);
  // U region: a_comp (pre-scan) aliases post-scan fp32/bf16 buffers (no temporal overlap)
  char* U = (char*)alloc((size_t)40200 * 512 * 2);   // 41.2 MB
  u16*   a_comp = (u16*)U;                           // ~31.7K rows x 512 bf16
  float* gi2    = (float*)(U);                       // 2048x600 f32 (4.9 MB)
  float* ghg    = (float*)(U + (size_t)5  * 1024 * 1024);
  float* al32   = (float*)(U + (size_t)12 * 1024 * 1024);  // 10000x200 f32 (8 MB)
  u16*   al_bf  = (u16*)  (U + (size_t)21 * 1024 * 1024);  // 10000x256 bf16 (5.2 MB)

  cntt_k<<<32, 256, 0, stream>>>(cur_ts, cntt, out);
  toff_k<<<1, 32, 0, stream>>>(cntt, toff);
  fill_pairs_t<<<32, 256, 0, stream>>>(cur_ts, toff, pairs);

  CvtTab tab;
  tab.t[0] = { r_emb,   re_bf,    460, 200,   512, 256 };
  tab.t[1] = { Wmap1,   wmap1_bf, 400, 200,   512, 256 };
  tab.t[2] = { Wmap2,   wmap2_bf, 200, 400,   256, 448 };
  tab.t[3] = { Wattn,   wattn_bf, 200, 200,   256, 256 };
  tab.t[4] = { Wih,     wih_bf,   600, 200,   640, 256 };
  tab.t[5] = { Whh,     whh_bf,   600, 200,   640, 256 };
  tab.t[6] = { Wh1,     wh1_bf,   200, 200,   256, 256 };
  tab.t[7] = { Wh2,     wh2_bf,   200, 200,   256, 256 };
  tab.t[8] = { Wal,     wal_bf,   200, 200,   256, 256 };
  tab.t[9] = { pre_emb, pre_bf, 10000, 200, 10112, 256 };
  cvt_all<<<dim3(512, 10), 256, 0, stream>>>(tab);

  gemm_bt<0,0><<<dim3(4, 4), 256, 0, stream>>>(re_bf, 256, wmap1_bf, 256, 200, 460, 400,
      bmap1, nullptr, hidden_bf, 512, nullptr, nullptr, nullptr, nullptr, nullptr,
      nullptr, nullptr, nullptr, nullptr, nullptr, 0, 0);
  gemm_bt<0,0><<<dim3(2, 4), 256, 0, stream>>>(hidden_bf, 512, wmap2_bf, 448, 400, 460, 200,
      bmap2, mrel32, mrel_bf, 256, nullptr, nullptr, nullptr, nullptr, nullptr,
      nullptr, nullptr, nullptr, nullptr, nullptr, 0, 0);
  gather_qrel<<<2048, 256, 0, stream>>>(mrel_bf, mrel32, trip, qrel_bf, qrel32);

  // z-batched: qa = qrel@Wattn^T + b  ||  ph1 = qrel@Wh1^T + b
  gemm_bt<0,0><<<dim3(2, 16, 2), 256, 0, stream>>>(qrel_bf, 256, wattn_bf, 256, 200, 2048, 200,
      battn, nullptr, qa_bf, 256, nullptr, nullptr, nullptr, nullptr, nullptr,
      qrel_bf, wh1_bf, bh1, nullptr, ph1_bf, 2048, 256);

  // z-batched: base = qa@mrel^T (fp32)  ||  M2T = Wih@mrel^T (bf16, 600x460 ld 512)
  gemm_bt<0,0><<<dim3(4, 16, 2), 256, 0, stream>>>(qa_bf, 256, mrel_bf, 256, 200, 2048, 460,
      nullptr, base32, nullptr, 0, nullptr, nullptr, nullptr, nullptr, nullptr,
      wih_bf, mrel_bf, nullptr, nullptr, m2t_bf, 600, 512);

  // compacted softmax -> compacted gi GEMM (row-indirect out)
  softmax_c<<<2048, 256, 0, stream>>>(part, base32, pairs, toff, a_comp);
  gemm_bt<3,0><<<dim3(5, 313), 256, 0, stream>>>(a_comp, 512, m2t_bf, 512, 460, 0, 600,
      bih, nullptr, gi_all, 640, nullptr, nullptr, pairs, nullptr, toff,
      nullptr, nullptr, nullptr, nullptr, nullptr, 0, 0);

  gru_scan3<<<256, 512, 0, stream>>>(gi_all, whh_bf, bhh, cur_ts, hout);

  // predicted_hist + fused match_loss (hout ready)
  gemm_bt<1,0><<<dim3(2, 16), 256, 0, stream>>>(ph1_bf, 256, wh2_bf, 256, 200, 2048, 200,
      bh2, ph32, ph_bf, 256, qrel32, hout, nullptr, out, nullptr,
      nullptr, nullptr, nullptr, nullptr, nullptr, 0, 0);

  // z-batched: gi2 = qrel@Wih^T + bih  ||  ghg = ph@Whh^T + bhh
  gemm_bt<0,0><<<dim3(5, 16, 2), 256, 0, stream>>>(qrel_bf, 256, wih_bf, 256, 200, 2048, 600,
      bih, gi2, nullptr, 0, nullptr, nullptr, nullptr, nullptr, nullptr,
      ph_bf, whh_bf, bhh, ghg, nullptr, 2048, 0);

  gemm_bt<0,0><<<dim3(2, 79), 256, 0, stream>>>(pre_bf, 256, wal_bf, 256, 200, 10000, 200,
      bal, al32, al_bf, 256, nullptr, nullptr, nullptr, nullptr, nullptr,
      nullptr, nullptr, nullptr, nullptr, nullptr, 0, 0);

  gru2_abig<<<2048, 256, 0, stream>>>(gi2, ghg, ph32, al32, trip, abig_bf);

  gemm_bt<2,1><<<dim3(79, 16), 256, 0, stream>>>(abig_bf, 256, al_bf, 256, 200, 2048, 10000,
      nullptr, out, nullptr, 0, nullptr, nullptr, trip, out + 1, nullptr,
      nullptr, nullptr, nullptr, nullptr, nullptr, 0, 0);
}

// Round 17
// 277.307 us; speedup vs baseline: 1.6995x; 1.2131x over previous
//
#include <hip/hip_runtime.h>
#include <cstdint>
#include <cstddef>

typedef unsigned short u16;
typedef __attribute__((ext_vector_type(8))) short short8;
typedef __attribute__((ext_vector_type(4))) float f32x4;

__device__ __forceinline__ f32x4 mfma16(short8 a, short8 b, f32x4 c){
  return __builtin_amdgcn_mfma_f32_16x16x32_bf16(a, b, c, 0, 0, 0);
}
__device__ __forceinline__ float bf2f(u16 u){
  unsigned v = ((unsigned)u) << 16; float f; __builtin_memcpy(&f, &v, 4); return f;
}
__device__ __forceinline__ u16 f2bf(float f){
  unsigned u; __builtin_memcpy(&u, &f, 4);
  u += 0x7FFFu + ((u >> 16) & 1u);
  return (u16)(u >> 16);
}
__device__ __forceinline__ float sigf(float x){ return 1.f / (1.f + __expf(-x)); }

// ---------------- fp32 -> zero-padded bf16 conversion ----------------
struct CvtD { const float* s; u16* d; int M, K, Mp, Kp; };
struct CvtTab { CvtD t[10]; };

__global__ void cvt_all(CvtTab tab){
  CvtD de = tab.t[blockIdx.y];
  int total = de.Mp * de.Kp;
  for (int i = blockIdx.x * blockDim.x + threadIdx.x; i < total; i += gridDim.x * blockDim.x){
    int r = i / de.Kp, c = i - r * de.Kp;
    float v = (r < de.M && c < de.K) ? de.s[(size_t)r * de.K + c] : 0.f;
    de.d[i] = f2bf(v);
  }
}

// q_rel gather
__global__ void gather_qrel(const u16* __restrict__ mbf, const float* __restrict__ m32,
                            const int* __restrict__ trip, u16* __restrict__ qbf,
                            float* __restrict__ q32){
  int i = blockIdx.x * blockDim.x + threadIdx.x;
  if (i < 2048 * 256){
    int b = i >> 8, c = i & 255;
    int rel = trip[b * 3 + 1];
    qbf[i] = mbf[rel * 256 + c];
    if (c < 200) q32[b * 200 + c] = m32[rel * 200 + c];
  }
}

// ---------------- compaction: t-major pair list of (t,b) with t < cur_ts[b] ---------
__global__ void cntt_k(const int* __restrict__ cur_ts, int* __restrict__ cntt,
                       float* __restrict__ out0){
  int t = blockIdx.x;
  __shared__ int psum[256];
  int tid = threadIdx.x, s = 0;
  #pragma unroll
  for (int k = 0; k < 8; ++k) s += (cur_ts[tid * 8 + k] > t) ? 1 : 0;
  psum[tid] = s; __syncthreads();
  for (int st = 128; st > 0; st >>= 1){
    if (tid < st) psum[tid] += psum[tid + st];
    __syncthreads();
  }
  if (tid == 0){
    cntt[t] = psum[0];
    if (t == 0){ out0[0] = 0.f; out0[1] = 0.f; }
  }
}
// fill_pairs also computes toff locally from cntt (block t prefix) and block 31
// publishes the total to toff[32] (consumed by softmax_c and MODE-3 GEMM).
__global__ void fill_pairs_t(const int* __restrict__ cur_ts, const int* __restrict__ cntt,
                             int* __restrict__ toff, int* __restrict__ pairs){
  int t = blockIdx.x;
  __shared__ int psum[256];
  __shared__ int base_s;
  int tid = threadIdx.x;
  if (tid == 0){
    int run = 0;
    for (int i = 0; i < t; ++i) run += cntt[i];
    base_s = run;
    if (t == 31) toff[32] = run + cntt[31];
  }
  int loc[8]; int tsum = 0;
  #pragma unroll
  for (int k = 0; k < 8; ++k){ loc[k] = (cur_ts[tid * 8 + k] > t) ? 1 : 0; tsum += loc[k]; }
  psum[tid] = tsum; __syncthreads();
  for (int st = 1; st < 256; st <<= 1){
    int v = (tid >= st) ? psum[tid - st] : 0;
    __syncthreads();
    psum[tid] += v;
    __syncthreads();
  }
  int run = psum[tid] - tsum + base_s;
  #pragma unroll
  for (int k = 0; k < 8; ++k)
    if (loc[k]){ pairs[run] = t * 2048 + tid * 8 + k; ++run; }
}

// ---------------- generic MFMA GEMM: 8 waves (512 thr), BK=32, 3-buf, 1 barrier/step -
// Waves 2x4: wave owns 64x32 subtile (acc[4][2]); staging = 1 A-load + 1 B-load per
// thread, counted vmcnt. 6 waves/SIMD at 3 blocks/CU for latency hiding.
// MODE 0: fp32/bf16 C (z-batchable).  MODE 1: ph + match_loss.
// MODE 2: score epilogue.  MODE 3: compacted gi (row-indirect out via pairs).
template<int MODE, int GROUP>
__global__ __launch_bounds__(512) void gemm_bt(
    const u16* A, int lda,
    const u16* B, int ldb,
    int K, int Mreal, int Nreal,
    const float* bias,
    float* C32,
    u16* C16, int ldc16,
    const float* __restrict__ extra,
    const float* __restrict__ extra2,
    const int* __restrict__ trip,
    float* __restrict__ loss,
    const int* __restrict__ tcnt,
    const u16* A2, const u16* B2, const float* bias2, float* C32b, u16* C16b,
    int Mreal2, int ldc16b)
{
  __shared__ u16 AB[3][2][128 * 32];   // 48 KB
  __shared__ float red[512];
  const int tid = threadIdx.x;
  const int wave = tid >> 6, lane = tid & 63;

  if (MODE == 0 && blockIdx.z){
    A = A2; B = B2; bias = bias2; C32 = C32b; C16 = C16b;
    Mreal = Mreal2; ldc16 = ldc16b;
  }

  int mx, my;
  if (GROUP == 0){
    my = blockIdx.y; mx = blockIdx.x;
  } else {
    const int gx = gridDim.x, gy = gridDim.y;
    int orig = blockIdx.y * gx + blockIdx.x;
    mx = orig / gy; my = orig - mx * gy;
  }

  const int m0 = my * 128, n0 = mx * 128;

  int Mg_ = Mreal;
  if (MODE == 3) Mg_ = tcnt[32];
  if (m0 >= Mg_) return;

  const int wm = (wave >> 2) * 64, wn = (wave & 3) * 32;
  const int srow = tid >> 2;                        // 0..127: staging row
  const int scol = (((tid & 3) ^ (srow & 3)) * 8);  // swizzled source col
  const int fr = lane & 15, fkg = lane >> 4;
  const int slot = (fkg ^ (fr & 3)) * 8;            // swizzled read slot

  f32x4 acc[4][2];
  #pragma unroll
  for (int i = 0; i < 4; ++i)
    #pragma unroll
    for (int j = 0; j < 2; ++j) acc[i][j] = (f32x4){0.f, 0.f, 0.f, 0.f};

  const int kT = (K + 31) >> 5;

  auto STAGE = [&](int kt, int p){
    const u16* ga = A + (size_t)(m0 + srow) * lda + kt * 32 + scol;
    __builtin_amdgcn_global_load_lds((const __attribute__((address_space(1))) void*)ga,
        (__attribute__((address_space(3))) void*)(&AB[p][0][0] + tid * 8), 16, 0, 0);
    const u16* gb = B + (size_t)(n0 + srow) * ldb + kt * 32 + scol;
    __builtin_amdgcn_global_load_lds((const __attribute__((address_space(1))) void*)gb,
        (__attribute__((address_space(3))) void*)(&AB[p][1][0] + tid * 8), 16, 0, 0);
  };

  STAGE(0, 0);
  if (kT > 1) STAGE(1, 1);
  for (int kt = 0; kt < kT; ++kt){
    const int p = kt % 3;
    if (kt + 1 < kT){
      __builtin_amdgcn_sched_barrier(0);
      asm volatile("s_waitcnt vmcnt(2)" ::: "memory");   // tile kt's 2 loads landed
    } else {
      __builtin_amdgcn_sched_barrier(0);
      asm volatile("s_waitcnt vmcnt(0)" ::: "memory");
    }
    __builtin_amdgcn_sched_barrier(0);
    __builtin_amdgcn_s_barrier();                        // single barrier per K-step
    __builtin_amdgcn_sched_barrier(0);

    if (kt + 2 < kT) STAGE(kt + 2, (kt + 2) % 3);

    short8 av[4], bv[2];
    #pragma unroll
    for (int i = 0; i < 4; ++i)
      av[i] = *(const short8*)(&AB[p][0][0] + (wm + i * 16 + fr) * 32 + slot);
    #pragma unroll
    for (int j = 0; j < 2; ++j)
      bv[j] = *(const short8*)(&AB[p][1][0] + (wn + j * 16 + fr) * 32 + slot);
    #pragma unroll
    for (int i = 0; i < 4; ++i)
      #pragma unroll
      for (int j = 0; j < 2; ++j)
        acc[i][j] = mfma16(av[i], bv[j], acc[i][j]);
  }

  if (MODE == 2){
    float lsum = 0.f;
    #pragma unroll
    for (int i = 0; i < 4; ++i){
      #pragma unroll
      for (int r = 0; r < 4; ++r){
        int row = m0 + wm + i * 16 + (lane >> 4) * 4 + r;
        int tcol = trip[row * 3 + 2];
        #pragma unroll
        for (int j = 0; j < 2; ++j){
          int col = n0 + wn + j * 16 + fr;
          if (col < Nreal){
            float v = acc[i][j][r];
            float e = __expf(-fabsf(v));
            float inv = __builtin_amdgcn_rcpf(1.f + e);
            C32[2 + (size_t)row * Nreal + col] = (v >= 0.f) ? inv : e * inv;
            float x = (tcol == col) ? v : -v;
            lsum += fminf(x, 0.f) - __logf(1.f + e);
          }
        }
      }
    }
    red[tid] = lsum;
    __syncthreads();
    for (int s = 256; s > 0; s >>= 1){
      if (tid < s) red[tid] += red[tid + s];
      __syncthreads();
    }
    if (tid == 0) atomicAdd(loss, -red[0] * (1.f / 20480000.f));
    return;
  }

  if (MODE == 3){
    #pragma unroll
    for (int i = 0; i < 4; ++i){
      #pragma unroll
      for (int r = 0; r < 4; ++r){
        int row = m0 + wm + i * 16 + (lane >> 4) * 4 + r;
        if (row < Mg_){
          int orow = trip[row];            // pairs[]: t*2048+b
          #pragma unroll
          for (int j = 0; j < 2; ++j){
            int col = n0 + wn + j * 16 + fr;
            if (col < Nreal)
              C16[(size_t)orow * ldc16 + col] = f2bf(acc[i][j][r] + bias[col]);
          }
        }
      }
    }
    return;
  }

  if (MODE == 1){
    float lsum = 0.f;
    #pragma unroll
    for (int i = 0; i < 4; ++i){
      #pragma unroll
      for (int j = 0; j < 2; ++j){
        int col = n0 + wn + j * 16 + fr;
        float bvl = (col < Nreal) ? bias[col] : 0.f;
        #pragma unroll
        for (int r = 0; r < 4; ++r){
          int row = m0 + wm + i * 16 + (lane >> 4) * 4 + r;
          if (col < Nreal){
            float pv = 0.1f * (acc[i][j][r] + bvl) + extra[(size_t)row * Nreal + col];
            C32[(size_t)row * Nreal + col] = pv;
            C16[(size_t)row * ldc16 + col] = f2bf(pv);
            float d = pv - extra2[(size_t)row * Nreal + col];
            lsum += d * d;
          } else {
            C16[(size_t)row * ldc16 + col] = 0;
          }
        }
      }
    }
    red[tid] = lsum;
    __syncthreads();
    for (int s = 256; s > 0; s >>= 1){
      if (tid < s) red[tid] += red[tid + s];
      __syncthreads();
    }
    if (tid == 0) atomicAdd(loss, red[0] * (1.f / 409600.f));
    return;
  }

  #pragma unroll
  for (int i = 0; i < 4; ++i){
    #pragma unroll
    for (int j = 0; j < 2; ++j){
      int col = n0 + wn + j * 16 + fr;
      float bvl = 0.f;
      if (bias && col < Nreal) bvl = bias[col];
      #pragma unroll
      for (int r = 0; r < 4; ++r){
        int row = m0 + wm + i * 16 + (lane >> 4) * 4 + r;
        float v = acc[i][j][r] + bvl;
        if (C32 && row < Mreal && col < Nreal) C32[(size_t)row * Nreal + col] = v;
        if (C16) C16[(size_t)row * ldc16 + col] =
            (row < Mreal && col < Nreal) ? f2bf(v) : (u16)0;
      }
    }
  }
}

// ---------------- compacted masked softmax over R=460 (single dispatch) -------------
__global__ __launch_bounds__(256) void softmax_c(
    const float* __restrict__ part, const float* __restrict__ base,
    const int* __restrict__ pairs, const int* __restrict__ toff,
    u16* __restrict__ aout)
{
  int wave = threadIdx.x >> 6, lane = threadIdx.x & 63;
  int hi = toff[32];
  for (int j = blockIdx.x * 4 + wave; j < hi; j += gridDim.x * 4){
    int p = pairs[j];
    int b = p & 2047, t = p >> 11;
    const float* pr = part + (size_t)b * 14720 + t * 460;
    const float* br = base + (size_t)b * 460;
    int r0 = lane * 8;
    float vals[8];
    if (lane < 57){
      float4 pa = *(const float4*)(pr + r0);
      float4 pb = *(const float4*)(pr + r0 + 4);
      float4 ba = *(const float4*)(br + r0);
      float4 bb = *(const float4*)(br + r0 + 4);
      float pv[8] = {pa.x, pa.y, pa.z, pa.w, pb.x, pb.y, pb.z, pb.w};
      float bw[8] = {ba.x, ba.y, ba.z, ba.w, bb.x, bb.y, bb.z, bb.w};
      #pragma unroll
      for (int u = 0; u < 8; ++u){
        float a = pv[u] * bw[u];
        bool valid = (r0 + u) < 460;
        vals[u] = (!valid) ? -__builtin_inff() : ((a == 0.f) ? -1000000000.0f : a);
      }
    } else {
      #pragma unroll
      for (int u = 0; u < 8; ++u){
        int r = r0 + u;
        if (r < 460){
          float a = pr[r] * br[r];
          vals[u] = (a == 0.f) ? -1000000000.0f : a;
        } else vals[u] = -__builtin_inff();
      }
    }
    float m = vals[0];
    #pragma unroll
    for (int u = 1; u < 8; ++u) m = fmaxf(m, vals[u]);
    #pragma unroll
    for (int s = 1; s < 64; s <<= 1) m = fmaxf(m, __shfl_xor(m, s));
    float e[8]; float sum = 0.f;
    #pragma unroll
    for (int u = 0; u < 8; ++u){
      float x = vals[u];
      float ev = (x == -__builtin_inff()) ? 0.f : __expf(x - m);
      e[u] = ev; sum += ev;
    }
    #pragma unroll
    for (int s = 1; s < 64; s <<= 1) sum += __shfl_xor(sum, s);
    float inv = __builtin_amdgcn_rcpf(sum);
    union { u16 o[8]; uint4 v; } pk;
    #pragma unroll
    for (int u = 0; u < 8; ++u) pk.o[u] = f2bf(e[u] * inv);
    *(uint4*)(aout + (size_t)j * 512 + r0) = pk.v;
  }
}

// ---------------- GRU recurrence v3: 256 blocks x 8 rows x 8 waves ------------------
__global__ __launch_bounds__(512, 2) void gru_scan3(
    const u16* __restrict__ gi_all,
    const u16* __restrict__ Whh,
    const float* __restrict__ bhh,
    const int* __restrict__ cur_ts,
    float* __restrict__ hout)
{
  __shared__ u16 hbf[16 * 256];
  __shared__ float hf[8 * 200];
  __shared__ float ghs[8][648];
  __shared__ u16 gis[2][8 * 640];
  __shared__ float bhs[600];
  __shared__ int cts[8];
  const int tid = threadIdx.x, wave = tid >> 6, lane = tid & 63;
  const int rb = blockIdx.x * 8;
  const int fr = lane & 15, fkg = lane >> 4;
  const int fk = fkg * 8;

  for (int i = tid; i < 16 * 256; i += 512) hbf[i] = 0;
  for (int i = tid; i < 8 * 200; i += 512) hf[i] = 0.f;
  for (int i = tid; i < 600; i += 512) bhs[i] = bhh[i];
  if (tid < 8) cts[tid] = cur_ts[rb + tid];
  __syncthreads();
  int Trun = 0;
  #pragma unroll
  for (int r = 0; r < 8; ++r) Trun = max(Trun, cts[r]);

  short8 wb[5][7];
  #pragma unroll
  for (int f = 0; f < 5; ++f)
    #pragma unroll
    for (int ks = 0; ks < 7; ++ks)
      wb[f][ks] = *(const short8*)(Whh + (size_t)(wave * 80 + f * 16 + fr) * 256 + ks * 32 + fk);

  if (Trun > 0){
    const u16* src = gi_all + (size_t)rb * 640;
    __builtin_amdgcn_global_load_lds(
        (const __attribute__((address_space(1))) void*)(src + tid * 8),
        (__attribute__((address_space(3))) void*)(&gis[0][0] + tid * 8), 16, 0, 0);
    if (tid < 128)
      __builtin_amdgcn_global_load_lds(
          (const __attribute__((address_space(1))) void*)(src + (512 + tid) * 8),
          (__attribute__((address_space(3))) void*)(&gis[0][0] + (512 + tid) * 8), 16, 0, 0);
  }
  __syncthreads();

  const int grow = wave;
  const int crow = (Trun > 0) ? cts[grow] : 0;

  for (int t = 0; t < Trun; ++t){
    f32x4 acc[5];
    #pragma unroll
    for (int f = 0; f < 5; ++f) acc[f] = (f32x4){0.f, 0.f, 0.f, 0.f};
    #pragma unroll
    for (int ks = 0; ks < 7; ++ks){
      short8 av = *(const short8*)(hbf + ((fr * 256 + ks * 32 + fk) ^ ((fr & 7) << 3)));
      #pragma unroll
      for (int f = 0; f < 5; ++f)
        acc[f] = mfma16(av, wb[f][ks], acc[f]);
    }
    if (fkg < 2){
      #pragma unroll
      for (int f = 0; f < 5; ++f){
        int col = wave * 80 + f * 16 + fr;
        #pragma unroll
        for (int r = 0; r < 4; ++r)
          ghs[fkg * 4 + r][col] = acc[f][r];
      }
    }
    __builtin_amdgcn_sched_barrier(0);
    asm volatile("s_waitcnt vmcnt(0) lgkmcnt(0)" ::: "memory");
    __builtin_amdgcn_sched_barrier(0);
    __builtin_amdgcn_s_barrier();
    __builtin_amdgcn_sched_barrier(0);

    if (t + 1 < Trun){
      const u16* src = gi_all + ((size_t)(t + 1) * 2048 + rb) * 640;
      u16* dst = &gis[(t + 1) & 1][0];
      __builtin_amdgcn_global_load_lds(
          (const __attribute__((address_space(1))) void*)(src + tid * 8),
          (__attribute__((address_space(3))) void*)(dst + tid * 8), 16, 0, 0);
      if (tid < 128)
        __builtin_amdgcn_global_load_lds(
            (const __attribute__((address_space(1))) void*)(src + (512 + tid) * 8),
            (__attribute__((address_space(3))) void*)(dst + (512 + tid) * 8), 16, 0, 0);
    }

    if (t < crow){
      const u16* gr = &gis[t & 1][0] + grow * 640;
      #pragma unroll
      for (int k = 0; k < 4; ++k){
        int d = lane + 64 * k;
        if (d < 200){
          float i0 = bf2f(gr[d]);
          float i1 = bf2f(gr[200 + d]);
          float i2 = bf2f(gr[400 + d]);
          float g0 = ghs[grow][d] + bhs[d];
          float g1 = ghs[grow][200 + d] + bhs[200 + d];
          float g2 = ghs[grow][400 + d] + bhs[400 + d];
          float e0 = __expf(-(i0 + g0));
          float r_ = __builtin_amdgcn_rcpf(1.f + e0);
          float e1 = __expf(-(i1 + g1));
          float z  = __builtin_amdgcn_rcpf(1.f + e1);
          float xn = i2 + r_ * g2;
          float e2 = __expf(2.f * xn);
          float n_ = 1.f - 2.f * __builtin_amdgcn_rcpf(e2 + 1.f);
          float hn = (1.f - z) * n_ + z * hf[grow * 200 + d];
          hf[grow * 200 + d] = hn;
          hbf[(grow * 256 + d) ^ (grow << 3)] = f2bf(hn);
        }
      }
    }
    __builtin_amdgcn_sched_barrier(0);
    asm volatile("s_waitcnt lgkmcnt(0)" ::: "memory");
    __builtin_amdgcn_sched_barrier(0);
    __builtin_amdgcn_s_barrier();
    __builtin_amdgcn_sched_barrier(0);
  }

  for (int i = tid; i < 1600; i += 512){
    int row = i / 200, d = i - row * 200;
    hout[(size_t)(rb + row) * 200 + d] = hf[row * 200 + d];
  }
}

// ---------------- fused: gh = GRU(q_rel, ph) and A_big = aligned_sub * gh ------------
__global__ __launch_bounds__(256) void gru2_abig(const float* __restrict__ gi,
                                                 const float* __restrict__ gg,
                                                 const float* __restrict__ hprev,
                                                 const float* __restrict__ al32,
                                                 const int* __restrict__ trip,
                                                 u16* __restrict__ abig){
  int i = blockIdx.x * 256 + threadIdx.x;
  if (i < 2048 * 256){
    int b = i >> 8, c = i & 255;
    u16 v = 0;
    if (c < 200){
      float i0 = gi[b * 600 + c], i1 = gi[b * 600 + 200 + c], i2 = gi[b * 600 + 400 + c];
      float g0 = gg[b * 600 + c], g1 = gg[b * 600 + 200 + c], g2 = gg[b * 600 + 400 + c];
      float r = sigf(i0 + g0);
      float z = sigf(i1 + g1);
      float n = tanhf(i2 + r * g2);
      float gh = (1.f - z) * n + z * hprev[b * 200 + c];
      int sub = trip[b * 3 + 0];
      v = f2bf(al32[(size_t)sub * 200 + c] * gh);
    }
    abig[i] = v;
  }
}

// =====================================================================================
extern "C" void kernel_launch(void* const* d_in, const int* in_sizes, int n_in,
                              void* d_out, int out_size, void* d_ws, size_t ws_size,
                              hipStream_t stream)
{
  (void)in_sizes; (void)n_in; (void)out_size; (void)ws_size;
  const float* pre_emb = (const float*)d_in[0];
  const float* r_emb   = (const float*)d_in[1];
  const int*   trip    = (const int*)d_in[2];
  const float* part    = (const float*)d_in[3];
  const int*   cur_ts  = (const int*)d_in[4];
  const float* Wmap1 = (const float*)d_in[5];   const float* bmap1 = (const float*)d_in[6];
  const float* Wmap2 = (const float*)d_in[7];   const float* bmap2 = (const float*)d_in[8];
  const float* Wattn = (const float*)d_in[9];   const float* battn = (const float*)d_in[10];
  const float* Wih   = (const float*)d_in[11];  const float* Whh   = (const float*)d_in[12];
  const float* bih   = (const float*)d_in[13];  const float* bhh   = (const float*)d_in[14];
  const float* Wh1   = (const float*)d_in[15];  const float* bh1   = (const float*)d_in[16];
  const float* Wh2   = (const float*)d_in[17];  const float* bh2   = (const float*)d_in[18];
  const float* Wal   = (const float*)d_in[19];  const float* bal   = (const float*)d_in[20];
  float* out = (float*)d_out;

  char* wsb = (char*)d_ws;
  size_t off = 0;
  auto alloc = [&](size_t bytes) -> void* {
    void* p = wsb + off;
    off = (off + bytes + 255) & ~(size_t)255;
    return p;
  };
  u16* re_bf     = (u16*)alloc((size_t)512 * 256 * 2);
  u16* wmap1_bf  = (u16*)alloc((size_t)512 * 256 * 2);
  u16* wmap2_bf  = (u16*)alloc((size_t)256 * 448 * 2);
  u16* wattn_bf  = (u16*)alloc((size_t)256 * 256 * 2);
  u16* wih_bf    = (u16*)alloc((size_t)640 * 256 * 2);
  u16* whh_bf    = (u16*)alloc((size_t)640 * 256 * 2);
  u16* wh1_bf    = (u16*)alloc((size_t)256 * 256 * 2);
  u16* wh2_bf    = (u16*)alloc((size_t)256 * 256 * 2);
  u16* wal_bf    = (u16*)alloc((size_t)256 * 256 * 2);
  u16* pre_bf    = (u16*)alloc((size_t)10112 * 256 * 2);
  u16* hidden_bf = (u16*)alloc((size_t)512 * 512 * 2);
  u16* mrel_bf   = (u16*)alloc((size_t)512 * 256 * 2);
  u16* m2t_bf    = (u16*)alloc((size_t)640 * 512 * 2);
  u16* qrel_bf   = (u16*)alloc((size_t)2048 * 256 * 2);
  u16* qa_bf     = (u16*)alloc((size_t)2048 * 256 * 2);
  u16* ph1_bf    = (u16*)alloc((size_t)2048 * 256 * 2);
  u16* ph_bf     = (u16*)alloc((size_t)2048 * 256 * 2);
  u16* abig_bf   = (u16*)alloc((size_t)2048 * 256 * 2);
  u16* gi_all    = (u16*)alloc((size_t)65536 * 640 * 2);
  float* mrel32 = (float*)alloc((size_t)460 * 200 * 4);
  float* base32 = (float*)alloc((size_t)2048 * 460 * 4);
  float* qrel32 = (float*)alloc((size_t)2048 * 200 * 4);
  float* hout   = (float*)alloc((size_t)2048 * 200 * 4);
  float* ph32   = (float*)alloc((size_t)2048 * 200 * 4);
  int* pairs    = (int*)alloc((size_t)65536 * 4);
  int* cntt     = (int*)alloc((size_t)64 * 4);
  int* toff     = (int*)alloc((size_t)64 * 4);
  // U region: a_comp (pre-scan) aliases post-scan fp32/bf16 buffers (no temporal overlap)
  char* U = (char*)alloc((size_t)40200 * 512 * 2);   // 41.2 MB
  u16*   a_comp = (u16*)U;                           // ~31.7K rows x 512 bf16
  float* gi2    = (float*)(U);                       // 2048x600 f32 (4.9 MB)
  float* ghg    = (float*)(U + (size_t)5  * 1024 * 1024);
  float* al32   = (float*)(U + (size_t)12 * 1024 * 1024);  // 10000x200 f32 (8 MB)
  u16*   al_bf  = (u16*)  (U + (size_t)21 * 1024 * 1024);  // 10000x256 bf16 (5.2 MB)

  cntt_k<<<32, 256, 0, stream>>>(cur_ts, cntt, out);
  fill_pairs_t<<<32, 256, 0, stream>>>(cur_ts, cntt, toff, pairs);

  CvtTab tab;
  tab.t[0] = { r_emb,   re_bf,    460, 200,   512, 256 };
  tab.t[1] = { Wmap1,   wmap1_bf, 400, 200,   512, 256 };
  tab.t[2] = { Wmap2,   wmap2_bf, 200, 400,   256, 448 };
  tab.t[3] = { Wattn,   wattn_bf, 200, 200,   256, 256 };
  tab.t[4] = { Wih,     wih_bf,   600, 200,   640, 256 };
  tab.t[5] = { Whh,     whh_bf,   600, 200,   640, 256 };
  tab.t[6] = { Wh1,     wh1_bf,   200, 200,   256, 256 };
  tab.t[7] = { Wh2,     wh2_bf,   200, 200,   256, 256 };
  tab.t[8] = { Wal,     wal_bf,   200, 200,   256, 256 };
  tab.t[9] = { pre_emb, pre_bf, 10000, 200, 10112, 256 };
  cvt_all<<<dim3(512, 10), 256, 0, stream>>>(tab);

  gemm_bt<0,0><<<dim3(4, 4), 512, 0, stream>>>(re_bf, 256, wmap1_bf, 256, 200, 460, 400,
      bmap1, nullptr, hidden_bf, 512, nullptr, nullptr, nullptr, nullptr, nullptr,
      nullptr, nullptr, nullptr, nullptr, nullptr, 0, 0);
  gemm_bt<0,0><<<dim3(2, 4), 512, 0, stream>>>(hidden_bf, 512, wmap2_bf, 448, 400, 460, 200,
      bmap2, mrel32, mrel_bf, 256, nullptr, nullptr, nullptr, nullptr, nullptr,
      nullptr, nullptr, nullptr, nullptr, nullptr, 0, 0);
  gather_qrel<<<2048, 256, 0, stream>>>(mrel_bf, mrel32, trip, qrel_bf, qrel32);

  // z-batched: qa = qrel@Wattn^T + b  ||  ph1 = qrel@Wh1^T + b
  gemm_bt<0,0><<<dim3(2, 16, 2), 512, 0, stream>>>(qrel_bf, 256, wattn_bf, 256, 200, 2048, 200,
      battn, nullptr, qa_bf, 256, nullptr, nullptr, nullptr, nullptr, nullptr,
      qrel_bf, wh1_bf, bh1, nullptr, ph1_bf, 2048, 256);

  // z-batched: base = qa@mrel^T (fp32)  ||  M2T = Wih@mrel^T (bf16, 600x460 ld 512)
  gemm_bt<0,0><<<dim3(4, 16, 2), 512, 0, stream>>>(qa_bf, 256, mrel_bf, 256, 200, 2048, 460,
      nullptr, base32, nullptr, 0, nullptr, nullptr, nullptr, nullptr, nullptr,
      wih_bf, mrel_bf, nullptr, nullptr, m2t_bf, 600, 512);

  // compacted softmax -> compacted gi GEMM (row-indirect out)
  softmax_c<<<2048, 256, 0, stream>>>(part, base32, pairs, toff, a_comp);
  gemm_bt<3,0><<<dim3(5, 313), 512, 0, stream>>>(a_comp, 512, m2t_bf, 512, 460, 0, 600,
      bih, nullptr, gi_all, 640, nullptr, nullptr, pairs, nullptr, toff,
      nullptr, nullptr, nullptr, nullptr, nullptr, 0, 0);

  gru_scan3<<<256, 512, 0, stream>>>(gi_all, whh_bf, bhh, cur_ts, hout);

  // predicted_hist + fused match_loss (hout ready)
  gemm_bt<1,0><<<dim3(2, 16), 512, 0, stream>>>(ph1_bf, 256, wh2_bf, 256, 200, 2048, 200,
      bh2, ph32, ph_bf, 256, qrel32, hout, nullptr, out, nullptr,
      nullptr, nullptr, nullptr, nullptr, nullptr, 0, 0);

  // z-batched: gi2 = qrel@Wih^T + bih  ||  ghg = ph@Whh^T + bhh
  gemm_bt<0,0><<<dim3(5, 16, 2), 512, 0, stream>>>(qrel_bf, 256, wih_bf, 256, 200, 2048, 600,
      bih, gi2, nullptr, 0, nullptr, nullptr, nullptr, nullptr, nullptr,
      ph_bf, whh_bf, bhh, ghg, nullptr, 2048, 0);

  gemm_bt<0,0><<<dim3(2, 79), 512, 0, stream>>>(pre_bf, 256, wal_bf, 256, 200, 10000, 200,
      bal, al32, al_bf, 256, nullptr, nullptr, nullptr, nullptr, nullptr,
      nullptr, nullptr, nullptr, nullptr, nullptr, 0, 0);

  gru2_abig<<<2048, 256, 0, stream>>>(gi2, ghg, ph32, al32, trip, abig_bf);

  gemm_bt<2,1><<<dim3(79, 16), 512, 0, stream>>>(abig_bf, 256, al_bf, 256, 200, 2048, 10000,
      nullptr, out, nullptr, 0, nullptr, nullptr, trip, out + 1, nullptr,
      nullptr, nullptr, nullptr, nullptr, nullptr, 0, 0);
}